// Round 1
// baseline (1150.000 us; speedup 1.0000x reference)
//
#include <hip/hip_runtime.h>
#include <math.h>

#define EPSf 1e-5f

constexpr int kH = 512, kW = 512, kCIN = 128, kCMID = 64, kCOUT = 64;
constexpr int kR = 16, kNSEG = 1024, kNB = 512;

// ---------------- bbox extraction (generic, run-compressed atomics) ------------
__global__ void k_bbox_init(int* __restrict__ mnr, int* __restrict__ mxr,
                            int* __restrict__ mnc, int* __restrict__ mxc) {
  int t = blockIdx.x * blockDim.x + threadIdx.x;
  if (t < kNSEG) {
    mnr[t] = 0x7fffffff; mxr[t] = -1;
    mnc[t] = 0x7fffffff; mxc[t] = -1;
  }
}

__global__ void k_bbox(const int* __restrict__ seg,
                       int* __restrict__ mnr, int* __restrict__ mxr,
                       int* __restrict__ mnc, int* __restrict__ mxc) {
  const int KPP = 16;  // pixels per thread, same row
  int t = blockIdx.x * blockDim.x + threadIdx.x;
  int base = t * KPP;
  if (base >= kH * kW) return;
  int r  = base / kW;
  int c0 = base % kW;
  int cur = seg[base];
  int cmin = c0, cmax = c0;
  for (int k = 1; k < KPP; ++k) {
    int s2 = seg[base + k];
    if (s2 != cur) {
      atomicMin(&mnr[cur], r);   atomicMax(&mxr[cur], r);
      atomicMin(&mnc[cur], cmin); atomicMax(&mxc[cur], cmax);
      cur = s2; cmin = c0 + k;
    }
    cmax = c0 + k;
  }
  atomicMin(&mnr[cur], r);   atomicMax(&mxr[cur], r);
  atomicMin(&mnc[cur], cmin); atomicMax(&mxc[cur], cmax);
}

__global__ void k_gather(const int* __restrict__ bn, const int* __restrict__ mnr,
                         const int* __restrict__ mxr, const int* __restrict__ mnc,
                         const int* __restrict__ mxc,
                         int* __restrict__ r0, int* __restrict__ c0,
                         int* __restrict__ hh, int* __restrict__ ww,
                         float* __restrict__ tail) {
  int t = blockIdx.x * blockDim.x + threadIdx.x;
  if (t >= kNB) return;
  int s = bn[t];
  int a = mnr[s], b = mxr[s], c = mnc[s], d = mxc[s];
  int h = b - a + 1, w = d - c + 1;
  r0[t] = a; c0[t] = c; hh[t] = h; ww[t] = w;
  tail[t]          = (float)h;
  tail[kNB + t]    = (float)w;
  tail[2*kNB + t]  = (float)a;
  tail[3*kNB + t]  = (float)c;
}

// ---------------- fused tiny CNN: one block per boundary node ------------------
// block = 256 threads; thread = output position (pi,pj), owns all 64 out-chans.
// LDS: 64 KB buffer reused for (a) BN0(patch) ci-halves, (b) x2 = conv1 result.
// Chunk XOR swizzle: float4 chunk q of position p lives at smem4[p*16 + (q^(p&15))].
__global__ __launch_bounds__(256, 2)
void k_cnn(const float* __restrict__ data,
           const float* __restrict__ bn0g, const float* __restrict__ bn0b,
           const float* __restrict__ bn0m, const float* __restrict__ bn0v,
           const float* __restrict__ w1,   const float* __restrict__ cb1,
           const float* __restrict__ bn1g, const float* __restrict__ bn1b,
           const float* __restrict__ bn1m, const float* __restrict__ bn1v,
           const float* __restrict__ w2,   const float* __restrict__ cb2,
           const int* __restrict__ r0a, const int* __restrict__ c0a,
           const int* __restrict__ hha, const int* __restrict__ wwa,
           float* __restrict__ out)
{
  __shared__ float smem[16 * 16 * 64];           // 64 KB
  float4* smem4 = reinterpret_cast<float4*>(smem);

  const int node = blockIdx.x;
  const int tid  = threadIdx.x;
  const int r0 = r0a[node], c0 = c0a[node];
  const int hh = hha[node], ww = wwa[node];

  const int pi = tid >> 4, pj = tid & 15;
  const bool pvalid = (pi < hh) && (pj < ww);

  float acc[64];
#pragma unroll
  for (int k = 0; k < 64; ++k) acc[k] = 0.f;

  // staging role: thread stages column sj, channel-chunk sq (4 channels)
  const int sj  = tid >> 4;
  const int sq  = tid & 15;
  const int ciL = sq * 4;

  // ---------------- conv1 over two 64-channel halves ----------------
  for (int half = 0; half < 2; ++half) {
    const int cig = half * 64 + ciL;
    float s0[4], b0[4];
#pragma unroll
    for (int k = 0; k < 4; ++k) {
      float g = bn0g[cig + k], m = bn0m[cig + k], v = bn0v[cig + k];
      float s = g / sqrtf(v + EPSf);
      s0[k] = s; b0[k] = bn0b[cig + k] - m * s;
    }
    __syncthreads();  // smem reuse guard
    const bool colok = (sj < ww);
    for (int row = 0; row < 16; ++row) {
      float4 v = make_float4(0.f, 0.f, 0.f, 0.f);
      if (colok && row < hh) {
        const float4 d = *reinterpret_cast<const float4*>(
            data + ((size_t)(r0 + row) * kW + (c0 + sj)) * kCIN + cig);
        v.x = d.x * s0[0] + b0[0];
        v.y = d.y * s0[1] + b0[1];
        v.z = d.z * s0[2] + b0[2];
        v.w = d.w * s0[3] + b0[3];
      }
      const int p = row * 16 + sj;
      smem4[p * 16 + (sq ^ (p & 15))] = v;
    }
    __syncthreads();

    const float* wh = w1 + half * 64 * kCMID;
#pragma unroll
    for (int kr = 0; kr < 3; ++kr) {
      const int ii = pi + kr - 1;
#pragma unroll
      for (int kc = 0; kc < 3; ++kc) {
        const int jj = pj + kc - 1;
        const bool act = ((unsigned)ii < 16u) && ((unsigned)jj < 16u);
        const int pp = ii * 16 + jj;
        const float* wk = wh + (kr * 3 + kc) * kCIN * kCMID;
        for (int q = 0; q < 16; ++q) {
          float4 v4 = make_float4(0.f, 0.f, 0.f, 0.f);
          if (act) v4 = smem4[pp * 16 + (q ^ (pp & 15))];
          const float* wq = wk + q * 4 * kCMID;
#pragma unroll
          for (int k = 0; k < 4; ++k) {
            const float v = (&v4.x)[k];
            const float4* wp = reinterpret_cast<const float4*>(wq + k * kCMID);
#pragma unroll
            for (int c4 = 0; c4 < 16; ++c4) {
              const float4 w = wp[c4];
              acc[c4*4+0] += v * w.x;
              acc[c4*4+1] += v * w.y;
              acc[c4*4+2] += v * w.z;
              acc[c4*4+3] += v * w.w;
            }
          }
        }
      }
    }
  }

  // ---------------- x2 = mask ? BN1(leaky(conv1+cb1)) : 0  -> LDS -----------
  __syncthreads();
#pragma unroll
  for (int q = 0; q < 16; ++q) {
    float4 r;
#pragma unroll
    for (int k = 0; k < 4; ++k) {
      const int co = q * 4 + k;
      float x = acc[co] + cb1[co];
      x = x > 0.f ? x : 0.01f * x;
      const float s = bn1g[co] / sqrtf(bn1v[co] + EPSf);
      const float xb = (x - bn1m[co]) * s + bn1b[co];
      (&r.x)[k] = pvalid ? xb : 0.f;
    }
    smem4[tid * 16 + (q ^ (tid & 15))] = r;
  }
  __syncthreads();

  // ---------------- conv2 ----------------
#pragma unroll
  for (int k = 0; k < 64; ++k) acc[k] = 0.f;

#pragma unroll
  for (int kr = 0; kr < 3; ++kr) {
    const int ii = pi + kr - 1;
#pragma unroll
    for (int kc = 0; kc < 3; ++kc) {
      const int jj = pj + kc - 1;
      const bool act = ((unsigned)ii < 16u) && ((unsigned)jj < 16u);
      const int pp = ii * 16 + jj;
      const float* wk = w2 + (kr * 3 + kc) * kCMID * kCOUT;
      for (int q = 0; q < 16; ++q) {
        float4 v4 = make_float4(0.f, 0.f, 0.f, 0.f);
        if (act) v4 = smem4[pp * 16 + (q ^ (pp & 15))];
        const float* wq = wk + q * 4 * kCOUT;
#pragma unroll
        for (int k = 0; k < 4; ++k) {
          const float v = (&v4.x)[k];
          const float4* wp = reinterpret_cast<const float4*>(wq + k * kCOUT);
#pragma unroll
          for (int c4 = 0; c4 < 16; ++c4) {
            const float4 w = wp[c4];
            acc[c4*4+0] += v * w.x;
            acc[c4*4+1] += v * w.y;
            acc[c4*4+2] += v * w.z;
            acc[c4*4+3] += v * w.w;
          }
        }
      }
    }
  }

  // ---------------- epilogue: sigmoid(leaky(conv2+cb2)) * mask --------------
  float* op = out + ((size_t)node * 256 + tid) * kCOUT;
#pragma unroll
  for (int q = 0; q < 16; ++q) {
    float4 o;
#pragma unroll
    for (int k = 0; k < 4; ++k) {
      const int co = q * 4 + k;
      float x = acc[co] + cb2[co];
      x = x > 0.f ? x : 0.01f * x;
      const float sg = 1.f / (1.f + expf(-x));
      (&o.x)[k] = pvalid ? sg : 0.f;
    }
    reinterpret_cast<float4*>(op)[q] = o;
  }
}

// ---------------- launch ----------------
extern "C" void kernel_launch(void* const* d_in, const int* in_sizes, int n_in,
                              void* d_out, int out_size, void* d_ws, size_t ws_size,
                              hipStream_t stream) {
  const float* data = (const float*)d_in[0];
  const float* bn0g = (const float*)d_in[1];
  const float* bn0b = (const float*)d_in[2];
  const float* bn0m = (const float*)d_in[3];
  const float* bn0v = (const float*)d_in[4];
  const float* w1   = (const float*)d_in[5];
  const float* cb1  = (const float*)d_in[6];
  const float* bn1g = (const float*)d_in[7];
  const float* bn1b = (const float*)d_in[8];
  const float* bn1m = (const float*)d_in[9];
  const float* bn1v = (const float*)d_in[10];
  const float* w2   = (const float*)d_in[11];
  const float* cb2  = (const float*)d_in[12];
  const int* bnodes = (const int*)d_in[13];
  const int* seg    = (const int*)d_in[14];
  float* out = (float*)d_out;

  int* wsi = (int*)d_ws;
  int* mnr = wsi,        *mxr = wsi + 1024;
  int* mnc = wsi + 2048, *mxc = wsi + 3072;
  int* r0  = wsi + 4096, *c0  = wsi + 4608;
  int* hh  = wsi + 5120, *ww  = wsi + 5632;

  k_bbox_init<<<4, 256, 0, stream>>>(mnr, mxr, mnc, mxc);
  k_bbox<<<64, 256, 0, stream>>>(seg, mnr, mxr, mnc, mxc);
  k_gather<<<2, 256, 0, stream>>>(bnodes, mnr, mxr, mnc, mxc, r0, c0, hh, ww,
                                  out + (size_t)kNB * 256 * kCOUT);
  k_cnn<<<kNB, 256, 0, stream>>>(data, bn0g, bn0b, bn0m, bn0v, w1, cb1,
                                 bn1g, bn1b, bn1m, bn1v, w2, cb2,
                                 r0, c0, hh, ww, out);
}

// Round 5
// 266.397 us; speedup vs baseline: 4.3169x; 4.3169x over previous
//
#include <hip/hip_runtime.h>
#include <math.h>

#define EPSf 1e-5f

typedef __attribute__((ext_vector_type(8))) __bf16 bf16x8;
typedef __attribute__((ext_vector_type(4))) float f32x4;
typedef unsigned short ushort_t;

constexpr int kH = 512, kW = 512, kCIN = 128, kNSEG = 1024, kNB = 512;

__device__ inline unsigned f2bf(float f) {   // RNE f32 -> bf16 (low 16 bits)
  unsigned u = __builtin_bit_cast(unsigned, f);
  return (u + 0x7fffu + ((u >> 16) & 1u)) >> 16;
}

// ---------------- bbox extraction (generic, run-compressed atomics) ------------
__global__ void k_bbox_init(int* __restrict__ mnr, int* __restrict__ mxr,
                            int* __restrict__ mnc, int* __restrict__ mxc) {
  int t = blockIdx.x * blockDim.x + threadIdx.x;
  if (t < kNSEG) {
    mnr[t] = 0x7fffffff; mxr[t] = -1;
    mnc[t] = 0x7fffffff; mxc[t] = -1;
  }
}

__global__ void k_bbox(const int* __restrict__ seg,
                       int* __restrict__ mnr, int* __restrict__ mxr,
                       int* __restrict__ mnc, int* __restrict__ mxc) {
  const int KPP = 16;
  int t = blockIdx.x * blockDim.x + threadIdx.x;
  int base = t * KPP;
  if (base >= kH * kW) return;
  int r  = base / kW;
  int c0 = base % kW;
  int cur = seg[base];
  int cmin = c0, cmax = c0;
  for (int k = 1; k < KPP; ++k) {
    int s2 = seg[base + k];
    if (s2 != cur) {
      atomicMin(&mnr[cur], r);    atomicMax(&mxr[cur], r);
      atomicMin(&mnc[cur], cmin); atomicMax(&mxc[cur], cmax);
      cur = s2; cmin = c0 + k;
    }
    cmax = c0 + k;
  }
  atomicMin(&mnr[cur], r);    atomicMax(&mxr[cur], r);
  atomicMin(&mnc[cur], cmin); atomicMax(&mxc[cur], cmax);
}

__global__ void k_gather(const int* __restrict__ bn, const int* __restrict__ mnr,
                         const int* __restrict__ mxr, const int* __restrict__ mnc,
                         const int* __restrict__ mxc,
                         int* __restrict__ r0, int* __restrict__ c0,
                         int* __restrict__ hh, int* __restrict__ ww,
                         float* __restrict__ tail) {
  int t = blockIdx.x * blockDim.x + threadIdx.x;
  if (t >= kNB) return;
  int s = bn[t];
  int a = mnr[s], b = mxr[s], c = mnc[s], d = mxc[s];
  int h = b - a + 1, w = d - c + 1;
  r0[t] = a; c0[t] = c; hh[t] = h; ww[t] = w;
  tail[t]          = (float)h;
  tail[kNB + t]    = (float)w;
  tail[2*kNB + t]  = (float)a;
  tail[3*kNB + t]  = (float)c;
}

// ---------------- weight pre-pack into MFMA B-fragment order -------------------
// w: [K][64] fp32 row-major (K = nkb*32). Output wp: [kb][n][lane][8] bf16.
// B-frag mapping: j = n*16 + (lane&15), k = kb*32 + 8*(lane>>4) + b.
__global__ void k_pack(const float* __restrict__ w, ushort_t* __restrict__ wp, int nkb) {
  int t = blockIdx.x * 256 + threadIdx.x;
  if (t >= nkb * 256) return;
  int lane = t & 63, n = (t >> 6) & 3, kb = t >> 8;
  int col = n * 16 + (lane & 15);
  int k0  = kb * 32 + 8 * (lane >> 4);
  unsigned r[8];
#pragma unroll
  for (int b = 0; b < 8; ++b) r[b] = f2bf(w[(k0 + b) * 64 + col]);
  uint4 v;
  v.x = r[0] | (r[1] << 16); v.y = r[2] | (r[3] << 16);
  v.z = r[4] | (r[5] << 16); v.w = r[6] | (r[7] << 16);
  reinterpret_cast<uint4*>(wp)[t] = v;
}

// ---------------- fused tiny CNN via bf16 MFMA implicit GEMM -------------------
// Block = 1 patch, 256 threads = 4 waves. Wave w owns image rows 4w..4w+3
// (4 M-tiles) x 4 N-tiles. M index within tile = column pj = lane&15.
// LDS act: [256 pos][16 chunks of 16B] bf16, chunk XOR-swizzled by (p&15).
// x2 reuses same buffer: [256 pos][8 chunks], swizzled by (p&7).
__global__ __launch_bounds__(256, 2)
void k_cnn(const float* __restrict__ data,
           const float* __restrict__ bn0g, const float* __restrict__ bn0b,
           const float* __restrict__ bn0m, const float* __restrict__ bn0v,
           const float* __restrict__ cb1,
           const float* __restrict__ bn1g, const float* __restrict__ bn1b,
           const float* __restrict__ bn1m, const float* __restrict__ bn1v,
           const float* __restrict__ cb2,
           const uint4* __restrict__ W1p, const uint4* __restrict__ W2p,
           const int* __restrict__ r0a, const int* __restrict__ c0a,
           const int* __restrict__ hha, const int* __restrict__ wwa,
           float* __restrict__ out)
{
  __shared__ uint4 act4[256 * 16];                  // 64 KB
  __shared__ float sb0s[128], sb0b[128];
  __shared__ float c1s[64], c1b[64], c1c[64], c2c[64];

  const int node = blockIdx.x;
  const int tid  = threadIdx.x;
  const int lane = tid & 63, wv = tid >> 6;
  const int kg = lane >> 4, ln15 = lane & 15;
  const int r0 = r0a[node], c0 = c0a[node];
  const int hh = hha[node], ww = wwa[node];

  // ---- fold BN constants into LDS ----
  if (tid < 128) {
    float s = bn0g[tid] * rsqrtf(bn0v[tid] + EPSf);
    sb0s[tid] = s; sb0b[tid] = bn0b[tid] - bn0m[tid] * s;
  }
  if (tid < 64) {
    float s1 = bn1g[tid] * rsqrtf(bn1v[tid] + EPSf);
    c1s[tid] = s1; c1b[tid] = bn1b[tid] - bn1m[tid] * s1;
    c1c[tid] = cb1[tid]; c2c[tid] = cb2[tid];
  }
  __syncthreads();

  // ---- stage BN0(patch)*mask as bf16 into LDS ----
  {
    const int p = tid, pi = p >> 4, pj = p & 15;
    const bool pv = (pi < hh) && (pj < ww);
    const float4* src = reinterpret_cast<const float4*>(
        data + ((size_t)(r0 + pi) * kW + (c0 + pj)) * kCIN);
#pragma unroll
    for (int q = 0; q < 16; ++q) {
      uint4 v = make_uint4(0u, 0u, 0u, 0u);
      if (pv) {
        float4 d0 = src[q * 2], d1 = src[q * 2 + 1];
        float e[8] = {d0.x, d0.y, d0.z, d0.w, d1.x, d1.y, d1.z, d1.w};
        unsigned b[8];
#pragma unroll
        for (int j = 0; j < 8; ++j)
          b[j] = f2bf(e[j] * sb0s[q * 8 + j] + sb0b[q * 8 + j]);
        v.x = b[0] | (b[1] << 16); v.y = b[2] | (b[3] << 16);
        v.z = b[4] | (b[5] << 16); v.w = b[6] | (b[7] << 16);
      }
      act4[p * 16 + (q ^ (p & 15))] = v;
    }
  }
  __syncthreads();

  f32x4 acc[4][4];
#pragma unroll
  for (int mi = 0; mi < 4; ++mi)
#pragma unroll
    for (int n = 0; n < 4; ++n) acc[mi][n] = (f32x4){0.f, 0.f, 0.f, 0.f};

  // ---- conv1: M=256, N=64, K=1152 ----
  for (int kr = 0; kr < 3; ++kr) {
    for (int kc = 0; kc < 3; ++kc) {
      const int jj = ln15 + kc - 1;
      const bool jok = (unsigned)jj < 16u;
#pragma unroll
      for (int cq = 0; cq < 4; ++cq) {
        const int kb = (kr * 3 + kc) * 4 + cq;
        uint4 bfr[4];
#pragma unroll
        for (int n = 0; n < 4; ++n) bfr[n] = W1p[(kb * 4 + n) * 64 + lane];
        uint4 afr[4];
#pragma unroll
        for (int mi = 0; mi < 4; ++mi) {
          const int ii = wv * 4 + mi + kr - 1;
          const bool ok = jok && ((unsigned)ii < 16u);
          const int pp = ok ? (ii * 16 + jj) : 0;
          uint4 v = act4[pp * 16 + ((cq * 4 + kg) ^ (pp & 15))];
          if (!ok) { v.x = 0u; v.y = 0u; v.z = 0u; v.w = 0u; }
          afr[mi] = v;
        }
#pragma unroll
        for (int mi = 0; mi < 4; ++mi)
#pragma unroll
          for (int n = 0; n < 4; ++n)
            acc[mi][n] = __builtin_amdgcn_mfma_f32_16x16x32_bf16(
                __builtin_bit_cast(bf16x8, afr[mi]),
                __builtin_bit_cast(bf16x8, bfr[n]), acc[mi][n], 0, 0, 0);
      }
    }
  }

  // ---- x2 = mask ? BN1(leaky(conv1+cb1)) : 0  -> LDS (bf16, 32 KB) ----
  __syncthreads();   // all conv1 LDS reads complete
  {
    ushort_t* x2 = reinterpret_cast<ushort_t*>(act4);
#pragma unroll
    for (int mi = 0; mi < 4; ++mi) {
      const int pi2 = wv * 4 + mi;
      const bool iok = pi2 < hh;
#pragma unroll
      for (int r = 0; r < 4; ++r) {
        const int pj2 = kg * 4 + r;
        const bool pv2 = iok && (pj2 < ww);
        const int p2 = pi2 * 16 + pj2;
#pragma unroll
        for (int n = 0; n < 4; ++n) {
          const int ch = n * 16 + ln15;
          float x = acc[mi][n][r] + c1c[ch];
          x = x > 0.f ? x : 0.01f * x;
          const float y = pv2 ? (x * c1s[ch] + c1b[ch]) : 0.f;
          x2[p2 * 64 + (((ch >> 3) ^ (p2 & 7)) << 3) + (ch & 7)] = (ushort_t)f2bf(y);
        }
      }
    }
  }
  __syncthreads();

#pragma unroll
  for (int mi = 0; mi < 4; ++mi)
#pragma unroll
    for (int n = 0; n < 4; ++n) acc[mi][n] = (f32x4){0.f, 0.f, 0.f, 0.f};

  // ---- conv2: M=256, N=64, K=576 ----
  {
    const uint4* x2u4 = reinterpret_cast<const uint4*>(act4);
    for (int kr = 0; kr < 3; ++kr) {
      for (int kc = 0; kc < 3; ++kc) {
        const int jj = ln15 + kc - 1;
        const bool jok = (unsigned)jj < 16u;
#pragma unroll
        for (int cq = 0; cq < 2; ++cq) {
          const int kb = (kr * 3 + kc) * 2 + cq;
          uint4 bfr[4];
#pragma unroll
          for (int n = 0; n < 4; ++n) bfr[n] = W2p[(kb * 4 + n) * 64 + lane];
          uint4 afr[4];
#pragma unroll
          for (int mi = 0; mi < 4; ++mi) {
            const int ii = wv * 4 + mi + kr - 1;
            const bool ok = jok && ((unsigned)ii < 16u);
            const int pp = ok ? (ii * 16 + jj) : 0;
            uint4 v = x2u4[pp * 8 + ((cq * 4 + kg) ^ (pp & 7))];
            if (!ok) { v.x = 0u; v.y = 0u; v.z = 0u; v.w = 0u; }
            afr[mi] = v;
          }
#pragma unroll
          for (int mi = 0; mi < 4; ++mi)
#pragma unroll
            for (int n = 0; n < 4; ++n)
              acc[mi][n] = __builtin_amdgcn_mfma_f32_16x16x32_bf16(
                  __builtin_bit_cast(bf16x8, afr[mi]),
                  __builtin_bit_cast(bf16x8, bfr[n]), acc[mi][n], 0, 0, 0);
        }
      }
    }
  }

  // ---- epilogue: sigmoid(leaky(conv2+cb2)) * mask -> out ----
#pragma unroll
  for (int mi = 0; mi < 4; ++mi) {
    const int pi2 = wv * 4 + mi;
    const bool iok = pi2 < hh;
#pragma unroll
    for (int r = 0; r < 4; ++r) {
      const int pj2 = kg * 4 + r;
      const bool pv2 = iok && (pj2 < ww);
      const int p2 = pi2 * 16 + pj2;
#pragma unroll
      for (int n = 0; n < 4; ++n) {
        const int ch = n * 16 + ln15;
        float x = acc[mi][n][r] + c2c[ch];
        x = x > 0.f ? x : 0.01f * x;
        const float sg = 1.f / (1.f + expf(-x));
        out[((size_t)(node * 256 + p2)) * 64 + ch] = pv2 ? sg : 0.f;
      }
    }
  }
}

// ---------------- launch ----------------
extern "C" void kernel_launch(void* const* d_in, const int* in_sizes, int n_in,
                              void* d_out, int out_size, void* d_ws, size_t ws_size,
                              hipStream_t stream) {
  const float* data = (const float*)d_in[0];
  const float* bn0g = (const float*)d_in[1];
  const float* bn0b = (const float*)d_in[2];
  const float* bn0m = (const float*)d_in[3];
  const float* bn0v = (const float*)d_in[4];
  const float* w1   = (const float*)d_in[5];
  const float* cb1  = (const float*)d_in[6];
  const float* bn1g = (const float*)d_in[7];
  const float* bn1b = (const float*)d_in[8];
  const float* bn1m = (const float*)d_in[9];
  const float* bn1v = (const float*)d_in[10];
  const float* w2   = (const float*)d_in[11];
  const float* cb2  = (const float*)d_in[12];
  const int* bnodes = (const int*)d_in[13];
  const int* seg    = (const int*)d_in[14];
  float* out = (float*)d_out;

  int* wsi = (int*)d_ws;
  int* mnr = wsi,        *mxr = wsi + 1024;
  int* mnc = wsi + 2048, *mxc = wsi + 3072;
  int* r0  = wsi + 4096, *c0  = wsi + 4608;
  int* hh  = wsi + 5120, *ww  = wsi + 5632;
  // packed weights (bf16) after 32 KB of bbox scratch
  ushort_t* W1p = (ushort_t*)((char*)d_ws + 32768);            // 36*256*16B = 147456 B
  ushort_t* W2p = (ushort_t*)((char*)d_ws + 32768 + 147456);   // 18*256*16B =  73728 B

  k_bbox_init<<<4, 256, 0, stream>>>(mnr, mxr, mnc, mxc);
  k_bbox<<<64, 256, 0, stream>>>(seg, mnr, mxr, mnc, mxc);
  k_gather<<<2, 256, 0, stream>>>(bnodes, mnr, mxr, mnc, mxc, r0, c0, hh, ww,
                                  out + (size_t)kNB * 256 * 64);
  k_pack<<<36, 256, 0, stream>>>(w1, W1p, 36);
  k_pack<<<18, 256, 0, stream>>>(w2, W2p, 18);
  k_cnn<<<kNB, 256, 0, stream>>>(data, bn0g, bn0b, bn0m, bn0v, cb1,
                                 bn1g, bn1b, bn1m, bn1v, cb2,
                                 (const uint4*)W1p, (const uint4*)W2p,
                                 r0, c0, hh, ww, out);
}